// Round 5
// baseline (129.504 us; speedup 1.0000x reference)
//
#include <hip/hip_runtime.h>
#include <math.h>

#define SEQ 256
#define DIMC 512
#define SCALEF 0.125f

typedef __attribute__((ext_vector_type(8))) short s16x8;
typedef __attribute__((ext_vector_type(4))) float f32x4;

static __device__ __forceinline__ unsigned short f2bf(float f) {
  union { float f; unsigned u; } c; c.f = f;
  unsigned r = c.u + 0x7FFF + ((c.u >> 16) & 1);  // RNE
  return (unsigned short)(r >> 16);
}

// ---------------- K0: fused prep: tcast(w_qkv), tcast(w_out), upT, LN --------
static __device__ void tcast_body(const float* __restrict__ W,
    unsigned short* __restrict__ WT, int K, int N, int n0, int k0, int t,
    float (*tile)[65]) {
#pragma unroll
  for (int i = 0; i < 16; ++i) {
    const int idx = i * 256 + t;
    const int kl = idx >> 6, nl = idx & 63;
    tile[kl][nl] = W[(size_t)(k0 + kl) * N + n0 + nl];
  }
  __syncthreads();
#pragma unroll
  for (int i = 0; i < 16; ++i) {
    const int idx = i * 256 + t;
    const int nl = idx >> 6, kl = idx & 63;
    WT[(size_t)(n0 + nl) * K + k0 + kl] = f2bf(tile[kl][nl]);
  }
}

__global__ __launch_bounds__(256) void prep_kernel(const float* __restrict__ x,
    const float* __restrict__ g, const float* __restrict__ bta,
    const float* __restrict__ w_qkv, const float* __restrict__ w_out,
    const float* __restrict__ up, unsigned short* __restrict__ xnb,
    unsigned short* __restrict__ wqt, unsigned short* __restrict__ wot,
    unsigned short* __restrict__ upT) {
  __shared__ float tile[64][65];
  __shared__ float sh_s[4], sh_q[4];
  const int t = threadIdx.x;
  const int bid = blockIdx.x;
  if (bid < 192) {
    tcast_body(w_qkv, wqt, 512, 1536, (bid % 24) * 64, (bid / 24) * 64, t, tile);
  } else if (bid < 256) {
    const int b2 = bid - 192;
    tcast_body(w_out, wot, 512, 512, (b2 % 8) * 64, (b2 / 8) * 64, t, tile);
  } else if (bid < 384) {
    // up (961x512 f32) -> upT (512 rows x 992 cols bf16, zero-padded K)
    const int b2 = bid - 256;
    const int k0 = (b2 >> 3) * 64, n0 = (b2 & 7) * 64;
#pragma unroll
    for (int i = 0; i < 16; ++i) {
      const int idx = i * 256 + t;
      const int kl = idx >> 6, nl = idx & 63;
      const int k = k0 + kl;
      tile[kl][nl] = (k < 961) ? up[(size_t)k * 512 + n0 + nl] : 0.0f;
    }
    __syncthreads();
#pragma unroll
    for (int i = 0; i < 16; ++i) {
      const int idx = i * 256 + t;
      const int nl = idx >> 6, kl = idx & 63;
      if (k0 + kl < 992)
        upT[(size_t)(n0 + nl) * 992 + k0 + kl] = f2bf(tile[kl][nl]);
    }
  } else {
    const int row = bid - 384;
    const float2 v = ((const float2*)(x + (size_t)row * DIMC))[t];
    float s = v.x + v.y;
    float q = v.x * v.x + v.y * v.y;
#pragma unroll
    for (int off = 32; off > 0; off >>= 1) {
      s += __shfl_down(s, off);
      q += __shfl_down(q, off);
    }
    const int wave = t >> 6, lane = t & 63;
    if (lane == 0) { sh_s[wave] = s; sh_q[wave] = q; }
    __syncthreads();
    const float fs = sh_s[0] + sh_s[1] + sh_s[2] + sh_s[3];
    const float fq = sh_q[0] + sh_q[1] + sh_q[2] + sh_q[3];
    const float mean = fs * (1.0f / DIMC);
    const float inv = rsqrtf(fq * (1.0f / DIMC) - mean * mean + 1e-5f);
    const float2 gv = ((const float2*)g)[t];
    const float2 bv = ((const float2*)bta)[t];
    ushort2 o;
    o.x = f2bf((v.x - mean) * inv * gv.x + bv.x);
    o.y = f2bf((v.y - mean) * inv * gv.y + bv.y);
    ((ushort2*)(xnb + (size_t)row * DIMC))[t] = o;
  }
}

// ---------------- direct-from-L2 MFMA GEMM: C = A(MxK) @ BT(NxK)^T (+bias) ---
// All operands (<=2 MB each) fit per-XCD L2 and each byte is read once per
// block -> LDS staging buys nothing (common-mistake #7). Per-lane 16B A/B
// fragments straight from global: zero LDS, zero barriers, zero vmcnt drains;
// unroll-4 K-loop keeps >=16 loads in flight; waves run fully decoupled.
template <int BM, int BN, int K, bool BIAS, bool OUTBF, bool VSPLIT>
__global__ __launch_bounds__(256) void gemm_direct(
    const unsigned short* __restrict__ A, const unsigned short* __restrict__ BT,
    const float* __restrict__ bias, void* __restrict__ Cv,
    unsigned short* __restrict__ vtb, int M, int N) {
  constexpr int TR = BM / 32;
  constexpr int TC = BN / 32;
  const int t = threadIdx.x;
  const int wave = t >> 6, lane = t & 63;
  const int wr = wave >> 1, wc = wave & 1;
  const int fr = lane & 15, q4 = lane >> 4;
  const int bm = blockIdx.x * BM, bn = blockIdx.y * BN;

  f32x4 acc[TR][TC] = {};
  const unsigned short* Ap = A + (size_t)(bm + wr * (BM / 2) + fr) * K + q4 * 8;
  const unsigned short* Bp = BT + (size_t)(bn + wc * (BN / 2) + fr) * K + q4 * 8;

#pragma unroll 4
  for (int k0 = 0; k0 < K; k0 += 32) {
    s16x8 af[TR], bfr[TC];
#pragma unroll
    for (int i = 0; i < TR; ++i)
      af[i] = *(const s16x8*)(Ap + (size_t)(i * 16) * K + k0);
#pragma unroll
    for (int j = 0; j < TC; ++j)
      bfr[j] = *(const s16x8*)(Bp + (size_t)(j * 16) * K + k0);
#pragma unroll
    for (int i = 0; i < TR; ++i)
#pragma unroll
      for (int j = 0; j < TC; ++j)
        acc[i][j] = __builtin_amdgcn_mfma_f32_16x16x32_bf16(af[i], bfr[j],
                                                            acc[i][j], 0, 0, 0);
  }

  if (VSPLIT && bn >= 1024) {
#pragma unroll
    for (int i = 0; i < TR; ++i) {
#pragma unroll
      for (int j = 0; j < TC; ++j) {
        const int hc = bn - 1024 + wc * (BN / 2) + j * 16 + fr;
        const int h = hc >> 6, d = hc & 63;
        const int row = bm + wr * (BM / 2) + i * 16 + q4 * 4;
        const int b = row >> 8, m = row & 255;
        ushort4 w;
        w.x = f2bf(acc[i][j][0]); w.y = f2bf(acc[i][j][1]);
        w.z = f2bf(acc[i][j][2]); w.w = f2bf(acc[i][j][3]);
        *(ushort4*)&vtb[(size_t)((b * 8 + h) * 64 + d) * 256 + m] = w;
      }
    }
    return;
  }
#pragma unroll
  for (int i = 0; i < TR; ++i) {
#pragma unroll
    for (int j = 0; j < TC; ++j) {
      const int col = bn + wc * (BN / 2) + j * 16 + fr;
      const float bv = BIAS ? bias[col] : 0.0f;
#pragma unroll
      for (int r = 0; r < 4; ++r) {
        const int row = bm + wr * (BM / 2) + i * 16 + q4 * 4 + r;
        if constexpr (OUTBF) {
          ((unsigned short*)Cv)[(size_t)row * N + col] = f2bf(acc[i][j][r] + bv);
        } else {
          ((float*)Cv)[(size_t)row * N + col] = acc[i][j][r] + bv;
        }
      }
    }
  }
}

// ---------------- K3: fused QK^T -> softmax -> (AV + rpos), 256 thr ----------
// 16-row n-tiles, grid 16x64 = 1024 blocks x 4 waves = 4 waves/SIMD.
// QK^T split by m (s[4]/wave), cross-wave softmax via tiny LDS arrays, P
// scattered into zeroed 16x512 window matrix (rpos as windowed GEMM vs
// direct-global upT), rpos+AV split by d across waves. setprio around MFMA
// clusters (T5: attn-structure +4-7%).
#define PSTR 264
#define ASTR2 520
__global__ __launch_bounds__(256) void attn_rpos_kernel(
    const unsigned short* __restrict__ qkvb,
    const unsigned short* __restrict__ vtb,
    const unsigned short* __restrict__ upT,
    unsigned short* __restrict__ ob) {
  __shared__ unsigned short ascat[16 * ASTR2];  // 16,640 B
  __shared__ unsigned short p_lds[16 * PSTR];   //  8,448 B
  __shared__ float smax[4][16], ssum[4][16];    //    512 B
  const int bh = blockIdx.y, b = bh >> 3, h = bh & 7;
  const int xn = blockIdx.x;        // n-tile: rows n0..n0+15, single xn
  const int n0 = xn * 16;
  const int t = threadIdx.x, wave = t >> 6, lane = t & 63;
  const int fr = lane & 15, q4 = lane >> 4;
  const int kwin0 = (xn * 31) & ~7;

  // zero the scatter matrix
  {
    const s16x8 z = {0, 0, 0, 0, 0, 0, 0, 0};
#pragma unroll
    for (int i = 0; i < 5; ++i) {
      const int idx = i * 256 + t;
      if (idx < 16 * ASTR2 / 8) *(s16x8*)(ascat + idx * 8) = z;
    }
  }

  // Q fragments (A rows = the 16 tile rows, fr = row) — same for all waves
  s16x8 qf[2];
  {
    const size_t qrow = (size_t)(b * SEQ + n0 + fr) * 1536 + h * 64;
#pragma unroll
    for (int ks = 0; ks < 2; ++ks)
      qf[ks] = *(const s16x8*)(qkvb + qrow + ks * 32 + q4 * 8);
  }

  // QK^T: this wave owns mt = 4*wave + j  (cols [mt*16, mt*16+16))
  f32x4 s[4];
#pragma unroll
  for (int j = 0; j < 4; ++j) s[j] = (f32x4){0.f, 0.f, 0.f, 0.f};
  {
    const unsigned short* kb =
        qkvb + (size_t)(b * SEQ + wave * 64 + fr) * 1536 + 512 + h * 64;
    __builtin_amdgcn_s_setprio(1);
#pragma unroll
    for (int ks = 0; ks < 2; ++ks)
#pragma unroll
      for (int j = 0; j < 4; ++j) {
        const s16x8 kf =
            *(const s16x8*)(kb + (size_t)j * (16 * 1536) + ks * 32 + q4 * 8);
        s[j] = __builtin_amdgcn_mfma_f32_16x16x32_bf16(qf[ks], kf, s[j], 0, 0, 0);
      }
    __builtin_amdgcn_s_setprio(0);
  }

  // wave-partial row max over this wave's 64 columns
  float mx[4] = {-1e30f, -1e30f, -1e30f, -1e30f};
#pragma unroll
  for (int j = 0; j < 4; ++j)
#pragma unroll
    for (int r = 0; r < 4; ++r) {
      s[j][r] *= SCALEF;
      mx[r] = fmaxf(mx[r], s[j][r]);
    }
#pragma unroll
  for (int r = 0; r < 4; ++r) {
    mx[r] = fmaxf(mx[r], __shfl_xor(mx[r], 1));
    mx[r] = fmaxf(mx[r], __shfl_xor(mx[r], 2));
    mx[r] = fmaxf(mx[r], __shfl_xor(mx[r], 4));
    mx[r] = fmaxf(mx[r], __shfl_xor(mx[r], 8));
  }
  if (fr == 0) {
#pragma unroll
    for (int r = 0; r < 4; ++r) smax[wave][q4 * 4 + r] = mx[r];
  }
  __syncthreads();  // also covers ascat zero completion

  float fm[4];
#pragma unroll
  for (int r = 0; r < 4; ++r) {
    const int row = q4 * 4 + r;
    fm[r] = fmaxf(fmaxf(smax[0][row], smax[1][row]),
                  fmaxf(smax[2][row], smax[3][row]));
  }
  float sum[4] = {0.f, 0.f, 0.f, 0.f};
#pragma unroll
  for (int j = 0; j < 4; ++j)
#pragma unroll
    for (int r = 0; r < 4; ++r) {
      s[j][r] = __expf(s[j][r] - fm[r]);
      sum[r] += s[j][r];
    }
#pragma unroll
  for (int r = 0; r < 4; ++r) {
    sum[r] += __shfl_xor(sum[r], 1);
    sum[r] += __shfl_xor(sum[r], 2);
    sum[r] += __shfl_xor(sum[r], 4);
    sum[r] += __shfl_xor(sum[r], 8);
  }
  if (fr == 0) {
#pragma unroll
    for (int r = 0; r < 4; ++r) ssum[wave][q4 * 4 + r] = sum[r];
  }
  __syncthreads();

  float invs[4];
#pragma unroll
  for (int r = 0; r < 4; ++r) {
    const int row = q4 * 4 + r;
    invs[r] = 1.0f / (ssum[0][row] + ssum[1][row] + ssum[2][row] + ssum[3][row]);
  }

  // write P: own mt-quarter columns, rows q4*4+r; both p_lds and scattered
#pragma unroll
  for (int j = 0; j < 4; ++j) {
    const int mt = wave * 4 + j;
#pragma unroll
    for (int r = 0; r < 4; ++r) {
      const int row = q4 * 4 + r;
      const unsigned short pb = f2bf(s[j][r] * invs[r]);
      p_lds[row * PSTR + mt * 16 + fr] = pb;
      const int c = (xn - mt + 15) * 31 + (row - fr + 15) - kwin0;
      ascat[row * ASTR2 + c] = pb;  // injective per row; unhit cols stay 0
    }
  }
  __syncthreads();

  // rpos (16 ks over 512-col window) + AV (8 ks), d-slice = wave*16 + fr
  f32x4 oA = (f32x4){0.f, 0.f, 0.f, 0.f}, oB = oA, oC = oA, oD = oA;
  {
    const unsigned short* uB =
        upT + (size_t)(h * 64 + wave * 16 + fr) * 992 + kwin0;
    const unsigned short* aR = ascat + fr * ASTR2;
    __builtin_amdgcn_s_setprio(1);
#pragma unroll
    for (int ks = 0; ks < 8; ++ks) {
      const s16x8 af = *(const s16x8*)(aR + ks * 32 + q4 * 8);
      const s16x8 bfg = *(const s16x8*)(uB + ks * 32 + q4 * 8);
      oA = __builtin_amdgcn_mfma_f32_16x16x32_bf16(af, bfg, oA, 0, 0, 0);
    }
#pragma unroll
    for (int ks = 8; ks < 16; ++ks) {
      const s16x8 af = *(const s16x8*)(aR + ks * 32 + q4 * 8);
      const s16x8 bfg = *(const s16x8*)(uB + ks * 32 + q4 * 8);
      oB = __builtin_amdgcn_mfma_f32_16x16x32_bf16(af, bfg, oB, 0, 0, 0);
    }
    __builtin_amdgcn_s_setprio(0);
  }
  {
    const unsigned short* vB = vtb + (size_t)(bh * 64 + wave * 16 + fr) * 256;
    const unsigned short* pR = p_lds + fr * PSTR;
    __builtin_amdgcn_s_setprio(1);
#pragma unroll
    for (int ks = 0; ks < 4; ++ks) {
      const s16x8 pf = *(const s16x8*)(pR + ks * 32 + q4 * 8);
      const s16x8 vfg = *(const s16x8*)(vB + ks * 32 + q4 * 8);
      oC = __builtin_amdgcn_mfma_f32_16x16x32_bf16(pf, vfg, oC, 0, 0, 0);
    }
#pragma unroll
    for (int ks = 4; ks < 8; ++ks) {
      const s16x8 pf = *(const s16x8*)(pR + ks * 32 + q4 * 8);
      const s16x8 vfg = *(const s16x8*)(vB + ks * 32 + q4 * 8);
      oD = __builtin_amdgcn_mfma_f32_16x16x32_bf16(pf, vfg, oD, 0, 0, 0);
    }
    __builtin_amdgcn_s_setprio(0);
  }
  const f32x4 o = (oA + oB) + (oC + oD);
#pragma unroll
  for (int r = 0; r < 4; ++r) {
    const int n = n0 + q4 * 4 + r;
    ob[(size_t)(b * SEQ + n) * DIMC + h * 64 + wave * 16 + fr] = f2bf(o[r]);
  }
}

extern "C" void kernel_launch(void* const* d_in, const int* in_sizes, int n_in,
                              void* d_out, int out_size, void* d_ws,
                              size_t ws_size, hipStream_t stream) {
  const float* x = (const float*)d_in[0];
  const float* ln_g = (const float*)d_in[1];
  const float* ln_b = (const float*)d_in[2];
  const float* w_qkv = (const float*)d_in[3];
  const float* up = (const float*)d_in[4];
  const float* w_out = (const float*)d_in[5];
  const float* b_out = (const float*)d_in[6];
  float* out = (float*)d_out;

  unsigned short* u = (unsigned short*)d_ws;
  unsigned short* qkvb = u;                  // 3,145,728 (V third unused)
  unsigned short* xnb = u + 3145728;         // 1,048,576
  unsigned short* ob = u + 4194304;          // 1,048,576
  unsigned short* wqt = u + 5242880;         //   786,432
  unsigned short* wot = u + 6029312;         //   262,144
  unsigned short* upT = u + 6291456;         //   507,904  (512 x 992 bf16)
  unsigned short* vtb = u + 6799360;         // 1,048,576
  if (ws_size < (size_t)7847936 * sizeof(unsigned short)) return;  // ~15.7 MB

  prep_kernel<<<2432, 256, 0, stream>>>(x, ln_g, ln_b, w_qkv, w_out, up,
                                        xnb, wqt, wot, upT);
  gemm_direct<64, 64, 512, false, true, true>
      <<<dim3(32, 24), 256, 0, stream>>>(xnb, wqt, nullptr, qkvb, vtb,
                                         2048, 1536);
  attn_rpos_kernel<<<dim3(16, 64), 256, 0, stream>>>(qkvb, vtb, upT, ob);
  gemm_direct<64, 32, 512, true, false, false>
      <<<dim3(32, 16), 256, 0, stream>>>(ob, wot, b_out, out, nullptr,
                                         2048, 512);
}

// Round 6
// 108.065 us; speedup vs baseline: 1.1984x; 1.1984x over previous
//
#include <hip/hip_runtime.h>
#include <math.h>

#define SEQ 256
#define DIMC 512
#define SCALEF 0.125f

typedef __attribute__((ext_vector_type(8))) short s16x8;
typedef __attribute__((ext_vector_type(4))) float f32x4;

typedef __attribute__((address_space(3))) unsigned int lds_u32_t;
typedef const __attribute__((address_space(1))) unsigned int g_u32_t;
static __device__ __forceinline__ void gl_lds16(const void* gsrc, void* ldst) {
  __builtin_amdgcn_global_load_lds((g_u32_t*)gsrc, (lds_u32_t*)ldst, 16, 0, 0);
}

static __device__ __forceinline__ unsigned short f2bf(float f) {
  union { float f; unsigned u; } c; c.f = f;
  unsigned r = c.u + 0x7FFF + ((c.u >> 16) & 1);  // RNE
  return (unsigned short)(r >> 16);
}

// ---------------- K0: fused prep: tcast(w_qkv), tcast(w_out), upT, LN --------
static __device__ void tcast_body(const float* __restrict__ W,
    unsigned short* __restrict__ WT, int K, int N, int n0, int k0, int t,
    float (*tile)[65]) {
#pragma unroll
  for (int i = 0; i < 16; ++i) {
    const int idx = i * 256 + t;
    const int kl = idx >> 6, nl = idx & 63;
    tile[kl][nl] = W[(size_t)(k0 + kl) * N + n0 + nl];
  }
  __syncthreads();
#pragma unroll
  for (int i = 0; i < 16; ++i) {
    const int idx = i * 256 + t;
    const int nl = idx >> 6, kl = idx & 63;
    WT[(size_t)(n0 + nl) * K + k0 + kl] = f2bf(tile[kl][nl]);
  }
}

__global__ __launch_bounds__(256) void prep_kernel(const float* __restrict__ x,
    const float* __restrict__ g, const float* __restrict__ bta,
    const float* __restrict__ w_qkv, const float* __restrict__ w_out,
    const float* __restrict__ up, unsigned short* __restrict__ xnb,
    unsigned short* __restrict__ wqt, unsigned short* __restrict__ wot,
    unsigned short* __restrict__ upT) {
  __shared__ float tile[64][65];
  const int t = threadIdx.x;
  const int bid = blockIdx.x;
  if (bid < 192) {
    tcast_body(w_qkv, wqt, 512, 1536, (bid % 24) * 64, (bid / 24) * 64, t, tile);
  } else if (bid < 256) {
    const int b2 = bid - 192;
    tcast_body(w_out, wot, 512, 512, (b2 % 8) * 64, (b2 / 8) * 64, t, tile);
  } else if (bid < 384) {
    // up (961x512 f32) -> upT (512 rows x 992 cols bf16, zero-padded K)
    const int b2 = bid - 256;
    const int k0 = (b2 >> 3) * 64, n0 = (b2 & 7) * 64;
#pragma unroll
    for (int i = 0; i < 16; ++i) {
      const int idx = i * 256 + t;
      const int kl = idx >> 6, nl = idx & 63;
      const int k = k0 + kl;
      tile[kl][nl] = (k < 961) ? up[(size_t)k * 512 + n0 + nl] : 0.0f;
    }
    __syncthreads();
#pragma unroll
    for (int i = 0; i < 16; ++i) {
      const int idx = i * 256 + t;
      const int nl = idx >> 6, kl = idx & 63;
      if (k0 + kl < 992)
        upT[(size_t)(n0 + nl) * 992 + k0 + kl] = f2bf(tile[kl][nl]);
    }
  } else {
    // LayerNorm, 8 rows/block, one row-pair per wave: pure wave-local
    // shfl reduction, zero LDS, zero barriers.
    const int r8 = (bid - 384) * 8;
    const int wave = t >> 6, lane = t & 63;
    const int d0 = lane * 8;
    const float4 g0 = *(const float4*)(g + d0);
    const float4 g1 = *(const float4*)(g + d0 + 4);
    const float4 b0 = *(const float4*)(bta + d0);
    const float4 b1 = *(const float4*)(bta + d0 + 4);
#pragma unroll
    for (int rr = 0; rr < 2; ++rr) {
      const int row = r8 + wave * 2 + rr;
      const float4 v0 = *(const float4*)(x + (size_t)row * DIMC + d0);
      const float4 v1 = *(const float4*)(x + (size_t)row * DIMC + d0 + 4);
      float s = v0.x + v0.y + v0.z + v0.w + v1.x + v1.y + v1.z + v1.w;
      float q = v0.x * v0.x + v0.y * v0.y + v0.z * v0.z + v0.w * v0.w +
                v1.x * v1.x + v1.y * v1.y + v1.z * v1.z + v1.w * v1.w;
#pragma unroll
      for (int off = 1; off < 64; off <<= 1) {
        s += __shfl_xor(s, off);
        q += __shfl_xor(q, off);
      }
      const float mean = s * (1.0f / DIMC);
      const float inv = rsqrtf(q * (1.0f / DIMC) - mean * mean + 1e-5f);
      s16x8 o;
      o[0] = (short)f2bf((v0.x - mean) * inv * g0.x + b0.x);
      o[1] = (short)f2bf((v0.y - mean) * inv * g0.y + b0.y);
      o[2] = (short)f2bf((v0.z - mean) * inv * g0.z + b0.z);
      o[3] = (short)f2bf((v0.w - mean) * inv * g0.w + b0.w);
      o[4] = (short)f2bf((v1.x - mean) * inv * g1.x + b1.x);
      o[5] = (short)f2bf((v1.y - mean) * inv * g1.y + b1.y);
      o[6] = (short)f2bf((v1.z - mean) * inv * g1.z + b1.z);
      o[7] = (short)f2bf((v1.w - mean) * inv * g1.w + b1.w);
      *(s16x8*)(xnb + (size_t)row * DIMC + d0) = o;
    }
  }
}

// ---------------- bf16 MFMA GEMM: C = A(MxK) @ BT(NxK)^T (+bias) -------------
// BK=64, double-buffered LDS, prefetch-before-compute (T3 minimum-2-phase):
// per K-tile issue next tile's global_load_lds FIRST, then ds_read + 8 MFMA
// on the current buffer, then ONE __syncthreads (vmcnt drain lands after the
// MFMA phase -> load latency hides under compute). 8-octet XOR swizzle
// (oct ^ row&7) on pre-swizzled global source + ds_read side; 2-way residual.
template <int BM, int BN, bool BIAS, bool OUTBF, bool VSPLIT>
__global__ __launch_bounds__(256) void mfma_gemm_bt(
    const unsigned short* __restrict__ A, const unsigned short* __restrict__ BT,
    const float* __restrict__ bias, void* __restrict__ Cv,
    unsigned short* __restrict__ vtb, int M, int K, int N) {
  constexpr int TR = BM / 32;
  constexpr int TC = BN / 32;
  __shared__ unsigned short As[2][BM * 64];
  __shared__ unsigned short Bs[2][BN * 64];
  const int t = threadIdx.x;
  const int wave = t >> 6, lane = t & 63;
  const int wr = wave >> 1, wc = wave & 1;
  const int bm = blockIdx.x * BM, bn = blockIdx.y * BN;
  const int fr = lane & 15, q4 = lane >> 4;

  f32x4 acc[TR][TC] = {};

  const int nk = K >> 6;

#define STAGE_TILE(sel, kb)                                                   \
  {                                                                           \
    const int k0s = (kb) << 6;                                                \
    _Pragma("unroll")                                                         \
    for (int c = 0; c < BM * 8 / 256; ++c) {                                  \
      const int p = c * 256 + t;                                              \
      const int row = p >> 3;                                                 \
      const int so = (p & 7) ^ (row & 7);                                     \
      gl_lds16(A + (size_t)(bm + row) * K + k0s + so * 8,                     \
               &As[sel][(size_t)(c * 256 + wave * 64) * 8]);                  \
    }                                                                         \
    _Pragma("unroll")                                                         \
    for (int c = 0; c < BN * 8 / 256; ++c) {                                  \
      const int p = c * 256 + t;                                              \
      const int row = p >> 3;                                                 \
      const int so = (p & 7) ^ (row & 7);                                     \
      gl_lds16(BT + (size_t)(bn + row) * K + k0s + so * 8,                    \
               &Bs[sel][(size_t)(c * 256 + wave * 64) * 8]);                  \
    }                                                                         \
  }

  STAGE_TILE(0, 0);
  __syncthreads();
  int cur = 0;
  for (int kb = 0; kb < nk; ++kb) {
    if (kb + 1 < nk) STAGE_TILE(cur ^ 1, kb + 1);
    s16x8 af[2][TR], bfr[2][TC];
#pragma unroll
    for (int ks = 0; ks < 2; ++ks) {
#pragma unroll
      for (int i = 0; i < TR; ++i) {
        const int row = wr * (BM / 2) + i * 16 + fr;
        const int op = (ks * 4 + q4) ^ (row & 7);
        af[ks][i] = *(const s16x8*)(&As[cur][row * 64 + op * 8]);
      }
#pragma unroll
      for (int j = 0; j < TC; ++j) {
        const int row = wc * (BN / 2) + j * 16 + fr;
        const int op = (ks * 4 + q4) ^ (row & 7);
        bfr[ks][j] = *(const s16x8*)(&Bs[cur][row * 64 + op * 8]);
      }
    }
#pragma unroll
    for (int ks = 0; ks < 2; ++ks)
#pragma unroll
      for (int i = 0; i < TR; ++i)
#pragma unroll
        for (int j = 0; j < TC; ++j)
          acc[i][j] = __builtin_amdgcn_mfma_f32_16x16x32_bf16(
              af[ks][i], bfr[ks][j], acc[i][j], 0, 0, 0);
    __syncthreads();
    cur ^= 1;
  }
#undef STAGE_TILE

  if (VSPLIT && bn >= 1024) {
#pragma unroll
    for (int i = 0; i < TR; ++i) {
#pragma unroll
      for (int j = 0; j < TC; ++j) {
        const int hc = bn - 1024 + wc * (BN / 2) + j * 16 + fr;
        const int h = hc >> 6, d = hc & 63;
        const int row = bm + wr * (BM / 2) + i * 16 + q4 * 4;
        const int b = row >> 8, m = row & 255;
        ushort4 w;
        w.x = f2bf(acc[i][j][0]); w.y = f2bf(acc[i][j][1]);
        w.z = f2bf(acc[i][j][2]); w.w = f2bf(acc[i][j][3]);
        *(ushort4*)&vtb[(size_t)((b * 8 + h) * 64 + d) * 256 + m] = w;
      }
    }
    return;
  }
#pragma unroll
  for (int i = 0; i < TR; ++i) {
#pragma unroll
    for (int j = 0; j < TC; ++j) {
      const int col = bn + wc * (BN / 2) + j * 16 + fr;
      const float bv = BIAS ? bias[col] : 0.0f;
#pragma unroll
      for (int r = 0; r < 4; ++r) {
        const int row = bm + wr * (BM / 2) + i * 16 + q4 * 4 + r;
        if constexpr (OUTBF) {
          ((unsigned short*)Cv)[(size_t)row * N + col] = f2bf(acc[i][j][r] + bv);
        } else {
          ((float*)Cv)[(size_t)row * N + col] = acc[i][j][r] + bv;
        }
      }
    }
  }
}

// ---------------- K3: fused QK^T -> softmax -> (AV + rpos), 256 thr ----------
// 16-row n-tiles, grid 16x64 = 1024 blocks x 4 waves = 4 waves/SIMD.
// QK^T split by m (s[4]/wave), cross-wave softmax via tiny LDS arrays, P
// scattered into zeroed 16x512 window matrix (rpos as windowed GEMM vs
// direct-global upT), rpos+AV split by d across waves. setprio around MFMA
// clusters (T5: attn-structure +4-7%).
#define PSTR 264
#define ASTR2 520
__global__ __launch_bounds__(256) void attn_rpos_kernel(
    const unsigned short* __restrict__ qkvb,
    const unsigned short* __restrict__ vtb,
    const unsigned short* __restrict__ upT,
    unsigned short* __restrict__ ob) {
  __shared__ unsigned short ascat[16 * ASTR2];  // 16,640 B
  __shared__ unsigned short p_lds[16 * PSTR];   //  8,448 B
  __shared__ float smax[4][16], ssum[4][16];    //    512 B
  const int bh = blockIdx.y, b = bh >> 3, h = bh & 7;
  const int xn = blockIdx.x;        // n-tile: rows n0..n0+15, single xn
  const int n0 = xn * 16;
  const int t = threadIdx.x, wave = t >> 6, lane = t & 63;
  const int fr = lane & 15, q4 = lane >> 4;
  const int kwin0 = (xn * 31) & ~7;

  // zero the scatter matrix
  {
    const s16x8 z = {0, 0, 0, 0, 0, 0, 0, 0};
#pragma unroll
    for (int i = 0; i < 5; ++i) {
      const int idx = i * 256 + t;
      if (idx < 16 * ASTR2 / 8) *(s16x8*)(ascat + idx * 8) = z;
    }
  }

  // Q fragments (A rows = the 16 tile rows, fr = row) — same for all waves
  s16x8 qf[2];
  {
    const size_t qrow = (size_t)(b * SEQ + n0 + fr) * 1536 + h * 64;
#pragma unroll
    for (int ks = 0; ks < 2; ++ks)
      qf[ks] = *(const s16x8*)(qkvb + qrow + ks * 32 + q4 * 8);
  }

  // QK^T: this wave owns mt = 4*wave + j  (cols [mt*16, mt*16+16))
  f32x4 s[4];
#pragma unroll
  for (int j = 0; j < 4; ++j) s[j] = (f32x4){0.f, 0.f, 0.f, 0.f};
  {
    const unsigned short* kb =
        qkvb + (size_t)(b * SEQ + wave * 64 + fr) * 1536 + 512 + h * 64;
    __builtin_amdgcn_s_setprio(1);
#pragma unroll
    for (int ks = 0; ks < 2; ++ks)
#pragma unroll
      for (int j = 0; j < 4; ++j) {
        const s16x8 kf =
            *(const s16x8*)(kb + (size_t)j * (16 * 1536) + ks * 32 + q4 * 8);
        s[j] = __builtin_amdgcn_mfma_f32_16x16x32_bf16(qf[ks], kf, s[j], 0, 0, 0);
      }
    __builtin_amdgcn_s_setprio(0);
  }

  // wave-partial row max over this wave's 64 columns
  float mx[4] = {-1e30f, -1e30f, -1e30f, -1e30f};
#pragma unroll
  for (int j = 0; j < 4; ++j)
#pragma unroll
    for (int r = 0; r < 4; ++r) {
      s[j][r] *= SCALEF;
      mx[r] = fmaxf(mx[r], s[j][r]);
    }
#pragma unroll
  for (int r = 0; r < 4; ++r) {
    mx[r] = fmaxf(mx[r], __shfl_xor(mx[r], 1));
    mx[r] = fmaxf(mx[r], __shfl_xor(mx[r], 2));
    mx[r] = fmaxf(mx[r], __shfl_xor(mx[r], 4));
    mx[r] = fmaxf(mx[r], __shfl_xor(mx[r], 8));
  }
  if (fr == 0) {
#pragma unroll
    for (int r = 0; r < 4; ++r) smax[wave][q4 * 4 + r] = mx[r];
  }
  __syncthreads();  // also covers ascat zero completion

  float fm[4];
#pragma unroll
  for (int r = 0; r < 4; ++r) {
    const int row = q4 * 4 + r;
    fm[r] = fmaxf(fmaxf(smax[0][row], smax[1][row]),
                  fmaxf(smax[2][row], smax[3][row]));
  }
  float sum[4] = {0.f, 0.f, 0.f, 0.f};
#pragma unroll
  for (int j = 0; j < 4; ++j)
#pragma unroll
    for (int r = 0; r < 4; ++r) {
      s[j][r] = __expf(s[j][r] - fm[r]);
      sum[r] += s[j][r];
    }
#pragma unroll
  for (int r = 0; r < 4; ++r) {
    sum[r] += __shfl_xor(sum[r], 1);
    sum[r] += __shfl_xor(sum[r], 2);
    sum[r] += __shfl_xor(sum[r], 4);
    sum[r] += __shfl_xor(sum[r], 8);
  }
  if (fr == 0) {
#pragma unroll
    for (int r = 0; r < 4; ++r) ssum[wave][q4 * 4 + r] = sum[r];
  }
  __syncthreads();

  float invs[4];
#pragma unroll
  for (int r = 0; r < 4; ++r) {
    const int row = q4 * 4 + r;
    invs[r] = 1.0f / (ssum[0][row] + ssum[1][row] + ssum[2][row] + ssum[3][row]);
  }

  // write P: own mt-quarter columns, rows q4*4+r; both p_lds and scattered
#pragma unroll
  for (int j = 0; j < 4; ++j) {
    const int mt = wave * 4 + j;
#pragma unroll
    for (int r = 0; r < 4; ++r) {
      const int row = q4 * 4 + r;
      const unsigned short pb = f2bf(s[j][r] * invs[r]);
      p_lds[row * PSTR + mt * 16 + fr] = pb;
      const int c = (xn - mt + 15) * 31 + (row - fr + 15) - kwin0;
      ascat[row * ASTR2 + c] = pb;  // injective per row; unhit cols stay 0
    }
  }
  __syncthreads();

  // rpos (16 ks over 512-col window) + AV (8 ks), d-slice = wave*16 + fr
  f32x4 oA = (f32x4){0.f, 0.f, 0.f, 0.f}, oB = oA, oC = oA, oD = oA;
  {
    const unsigned short* uB =
        upT + (size_t)(h * 64 + wave * 16 + fr) * 992 + kwin0;
    const unsigned short* aR = ascat + fr * ASTR2;
    __builtin_amdgcn_s_setprio(1);
#pragma unroll
    for (int ks = 0; ks < 8; ++ks) {
      const s16x8 af = *(const s16x8*)(aR + ks * 32 + q4 * 8);
      const s16x8 bfg = *(const s16x8*)(uB + ks * 32 + q4 * 8);
      oA = __builtin_amdgcn_mfma_f32_16x16x32_bf16(af, bfg, oA, 0, 0, 0);
    }
#pragma unroll
    for (int ks = 8; ks < 16; ++ks) {
      const s16x8 af = *(const s16x8*)(aR + ks * 32 + q4 * 8);
      const s16x8 bfg = *(const s16x8*)(uB + ks * 32 + q4 * 8);
      oB = __builtin_amdgcn_mfma_f32_16x16x32_bf16(af, bfg, oB, 0, 0, 0);
    }
    __builtin_amdgcn_s_setprio(0);
  }
  {
    const unsigned short* vB = vtb + (size_t)(bh * 64 + wave * 16 + fr) * 256;
    const unsigned short* pR = p_lds + fr * PSTR;
    __builtin_amdgcn_s_setprio(1);
#pragma unroll
    for (int ks = 0; ks < 4; ++ks) {
      const s16x8 pf = *(const s16x8*)(pR + ks * 32 + q4 * 8);
      const s16x8 vfg = *(const s16x8*)(vB + ks * 32 + q4 * 8);
      oC = __builtin_amdgcn_mfma_f32_16x16x32_bf16(pf, vfg, oC, 0, 0, 0);
    }
#pragma unroll
    for (int ks = 4; ks < 8; ++ks) {
      const s16x8 pf = *(const s16x8*)(pR + ks * 32 + q4 * 8);
      const s16x8 vfg = *(const s16x8*)(vB + ks * 32 + q4 * 8);
      oD = __builtin_amdgcn_mfma_f32_16x16x32_bf16(pf, vfg, oD, 0, 0, 0);
    }
    __builtin_amdgcn_s_setprio(0);
  }
  const f32x4 o = (oA + oB) + (oC + oD);
#pragma unroll
  for (int r = 0; r < 4; ++r) {
    const int n = n0 + q4 * 4 + r;
    ob[(size_t)(b * SEQ + n) * DIMC + h * 64 + wave * 16 + fr] = f2bf(o[r]);
  }
}

extern "C" void kernel_launch(void* const* d_in, const int* in_sizes, int n_in,
                              void* d_out, int out_size, void* d_ws,
                              size_t ws_size, hipStream_t stream) {
  const float* x = (const float*)d_in[0];
  const float* ln_g = (const float*)d_in[1];
  const float* ln_b = (const float*)d_in[2];
  const float* w_qkv = (const float*)d_in[3];
  const float* up = (const float*)d_in[4];
  const float* w_out = (const float*)d_in[5];
  const float* b_out = (const float*)d_in[6];
  float* out = (float*)d_out;

  unsigned short* u = (unsigned short*)d_ws;
  unsigned short* qkvb = u;                  // 3,145,728 (V third unused)
  unsigned short* xnb = u + 3145728;         // 1,048,576
  unsigned short* ob = u + 4194304;          // 1,048,576
  unsigned short* wqt = u + 5242880;         //   786,432
  unsigned short* wot = u + 6029312;         //   262,144
  unsigned short* upT = u + 6291456;         //   507,904  (512 x 992 bf16)
  unsigned short* vtb = u + 6799360;         // 1,048,576
  if (ws_size < (size_t)7847936 * sizeof(unsigned short)) return;  // ~15.7 MB

  prep_kernel<<<640, 256, 0, stream>>>(x, ln_g, ln_b, w_qkv, w_out, up,
                                       xnb, wqt, wot, upT);
  mfma_gemm_bt<64, 64, false, true, true>
      <<<dim3(32, 24), 256, 0, stream>>>(xnb, wqt, nullptr, qkvb, vtb,
                                         2048, 512, 1536);
  attn_rpos_kernel<<<dim3(16, 64), 256, 0, stream>>>(qkvb, vtb, upT, ob);
  mfma_gemm_bt<64, 32, true, false, false>
      <<<dim3(32, 16), 256, 0, stream>>>(ob, wot, b_out, out, nullptr,
                                         2048, 512, 512);
}